// Round 2
// baseline (118.524 us; speedup 1.0000x reference)
//
#include <hip/hip_runtime.h>
#include <math.h>

#define HW 512
#define NB 16
#define TX 64           // tile width
#define TY 64           // tile height
#define LDSW 72         // TX + 8 (4-col halo left, 4 right; float4-aligned)
#define LDSH 70         // TY + 6
#define N_PIX (NB * HW * HW)   // 4194304
#define NBLK (8 * 8 * NB)      // 1024 phase-1 blocks

using f32x4 = __attribute__((ext_vector_type(4))) float;

// Force a float into an SGPR (uniform across wave).
__device__ __forceinline__ float sgpr_f(float v) {
    return __uint_as_float(__builtin_amdgcn_readfirstlane(__float_as_uint(v)));
}

// Phase 1: 64x64 tile per block; thread = 4 cols x 4 rows (4x4 output patch).
// dif via identity: sum w*relu(v-c) = sum w*max(v,c) - c*sum(w)  (2 ops/tap).
// Window rows stream through registers as 3 aligned ds_read_b128 per row
// (vs 7 scalar b32 per pixel-row in the 1x16 tiling): 34 b128/thread total.
__global__ __launch_bounds__(256, 4) void li_phase1(
    const float* __restrict__ x, const float* __restrict__ kw,
    float* __restrict__ out_ratio, float* __restrict__ out_avg,
    float* __restrict__ out_dif, float* __restrict__ partials)
{
    __shared__ float tile[LDSH * LDSW];   // 20160 B
    __shared__ float wsum[4];

    const int tid = threadIdx.x;
    const int bx = blockIdx.x, by = blockIdx.y, b = blockIdx.z;
    const int x0 = bx * TX, y0 = by * TY;
    const float* xb = x + (size_t)b * (HW * HW);

    // 49 weights pinned to SGPRs; W = sum of all weights (center weight is 0).
    float w[49];
    float W = 0.f;
#pragma unroll
    for (int i = 0; i < 49; i++) { w[i] = sgpr_f(kw[i]); W += w[i]; }

    // Stage 70 x 72 tile with zero halo, float4 granularity.
    for (int idx = tid; idx < LDSH * (LDSW / 4); idx += 256) {
        int r = idx / (LDSW / 4);
        int c4 = idx - r * (LDSW / 4);
        int gy = y0 - 3 + r;
        int gx = x0 - 4 + c4 * 4;
        float4 v = make_float4(0.f, 0.f, 0.f, 0.f);
        if ((unsigned)gy < HW && (unsigned)gx < HW)
            v = *(const float4*)(xb + gy * HW + gx);
        *(float4*)&tile[r * LDSW + c4 * 4] = v;
    }
    __syncthreads();

    const int cx = tid & 15;         // column group: output cols 4cx..4cx+3
    const int cy = tid >> 4;         // row group:    output rows 4cy..4cy+3
    const int colw = 4 * cx;         // LDS word col of v[0] (= tile col - 4)
    const int row0 = 4 * cy;         // first streamed LDS row

    // Centers: 4 aligned float4 loads (LDS cols colw+4..colw+7 = own columns).
    float cen[16];
#pragma unroll
    for (int p = 0; p < 4; p++) {
        float4 c4v = *(const float4*)&tile[(row0 + 3 + p) * LDSW + colw + 4];
        cen[p*4+0] = c4v.x; cen[p*4+1] = c4v.y; cen[p*4+2] = c4v.z; cen[p*4+3] = c4v.w;
    }

    float dif[16], bsum[16];
#pragma unroll
    for (int k = 0; k < 16; k++) { dif[k] = 0.f; bsum[k] = 0.f; }

    // Stream 10 window rows; prefetch row r+1 while consuming row r.
    // Row covers LDS words colw..colw+11 (we need colw+1..colw+10), 3x b128.
    float4 q0, q1, q2, n0, n1, n2;
    {
        const float* base = &tile[row0 * LDSW + colw];
        q0 = *(const float4*)base;
        q1 = *(const float4*)(base + 4);
        q2 = *(const float4*)(base + 8);
    }

#pragma unroll
    for (int r = 0; r < 10; r++) {
        if (r < 9) {
            const float* base = &tile[(row0 + r + 1) * LDSW + colw];
            n0 = *(const float4*)base;
            n1 = *(const float4*)(base + 4);
            n2 = *(const float4*)(base + 8);
        }
        float v[12] = {q0.x, q0.y, q0.z, q0.w,
                       q1.x, q1.y, q1.z, q1.w,
                       q2.x, q2.y, q2.z, q2.w};

        // Sliding 7-wide row sums for the 4 output columns.
        float s0 = ((v[1] + v[2]) + (v[3] + v[4])) + ((v[5] + v[6]) + v[7]);
        float s1 = s0 + (v[8]  - v[1]);
        float s2 = s1 + (v[9]  - v[2]);
        float s3 = s2 + (v[10] - v[3]);

#pragma unroll
        for (int p = 0; p < 4; p++) {
            const int di = r - p;              // window row index 0..6
            if (di < 0 || di >= 7) continue;   // compile-time resolved
            bsum[p*4+0] += s0; bsum[p*4+1] += s1;
            bsum[p*4+2] += s2; bsum[p*4+3] += s3;
#pragma unroll
            for (int dj = 0; dj < 7; dj++) {
                if (di == 3 && dj == 3) continue;   // center weight == 0
                const float wv = w[di*7+dj];
#pragma unroll
                for (int j = 0; j < 4; j++)
                    dif[p*4+j] = fmaf(wv, fmaxf(v[1+j+dj], cen[p*4+j]), dif[p*4+j]);
            }
        }
        q0 = n0; q1 = n1; q2 = n2;
    }

    // Epilogue: float4 stores. avg/dif nontemporal (never re-read);
    // ratio via plain store (phase 2 re-reads it, keep it L2-friendly).
    const size_t gbase = (size_t)b * (HW * HW) + (size_t)(y0 + row0) * HW + x0 + colw;
    float ss = 0.f;
#pragma unroll
    for (int p = 0; p < 4; p++) {
        float av[4], dv[4], rv[4];
#pragma unroll
        for (int j = 0; j < 4; j++) {
            const int k = p*4+j;
            av[j] = __expf(-bsum[k] * (1.0f / 49.0f));
            dv[j] = fmaf(-W, cen[k], dif[k]);            // subtract c*sum(w)
            const float spv = 0.1f * av[j] + 0.9f * dv[j];  // > 0 always
            rv[j] = cen[k] * __builtin_amdgcn_rcpf(spv);
            ss = fmaf(spv, spv, ss);
        }
        const size_t gi = gbase + (size_t)p * HW;
        f32x4 a4 = {av[0], av[1], av[2], av[3]};
        f32x4 d4 = {dv[0], dv[1], dv[2], dv[3]};
        f32x4 r4 = {rv[0], rv[1], rv[2], rv[3]};
        __builtin_nontemporal_store(a4, (f32x4*)(out_avg + gi));
        __builtin_nontemporal_store(d4, (f32x4*)(out_dif + gi));
        *(f32x4*)(out_ratio + gi) = r4;
    }

    // Block reduction of ss -> partials[bid].
#pragma unroll
    for (int off = 32; off > 0; off >>= 1)
        ss += __shfl_down(ss, off, 64);
    if ((tid & 63) == 0) wsum[tid >> 6] = ss;
    __syncthreads();
    if (tid == 0)
        partials[bx + 8 * (by + 8 * b)] = (wsum[0] + wsum[1]) + (wsum[2] + wsum[3]);
}

// Phase 2 (reduce fused): each block sums the 1024 partials itself (L2-resident,
// 4 KB), then masks its 4096-element slice in place: mask = (ratio > 1/sqrt(ss)).
__global__ __launch_bounds__(256) void li_phase2(
    const float* __restrict__ partials, float* __restrict__ io)
{
    __shared__ float wsum[4];
    __shared__ float s_inv;
    const int tid = threadIdx.x;

    float s = 0.f;
#pragma unroll
    for (int i = 0; i < NBLK / 256; i++)
        s += partials[tid + i * 256];
#pragma unroll
    for (int off = 32; off > 0; off >>= 1)
        s += __shfl_down(s, off, 64);
    if ((tid & 63) == 0) wsum[tid >> 6] = s;
    __syncthreads();
    if (tid == 0)
        s_inv = 1.0f / sqrtf((wsum[0] + wsum[1]) + (wsum[2] + wsum[3]));
    __syncthreads();

    const float inv = s_inv;
    const int base = blockIdx.x * 4096 + tid * 4;
#pragma unroll
    for (int k = 0; k < 4; k++) {
        const int i = base + k * 1024;
        float4 r = *(const float4*)(io + i);
        float4 m;
        m.x = (r.x > inv) ? 1.f : 0.f;
        m.y = (r.y > inv) ? 1.f : 0.f;
        m.z = (r.z > inv) ? 1.f : 0.f;
        m.w = (r.w > inv) ? 1.f : 0.f;
        *(float4*)(io + i) = m;
    }
}

extern "C" void kernel_launch(void* const* d_in, const int* in_sizes, int n_in,
                              void* d_out, int out_size, void* d_ws, size_t ws_size,
                              hipStream_t stream) {
    const float* x  = (const float*)d_in[0];
    const float* kw = (const float*)d_in[1];
    float* out   = (float*)d_out;
    float* ratio = out;                       // becomes mask after phase 2
    float* avg   = out + N_PIX;
    float* dif   = out + 2 * (size_t)N_PIX;
    float* ws    = (float*)d_ws;              // [0,NBLK): partials (fully written)

    dim3 g(HW / TX, HW / TY, NB);   // 8 x 8 x 16 = 1024 blocks
    li_phase1<<<g, 256, 0, stream>>>(x, kw, ratio, avg, dif, ws);
    li_phase2<<<N_PIX / 4096, 256, 0, stream>>>(ws, ratio);
}

// Round 3
// 100.589 us; speedup vs baseline: 1.1783x; 1.1783x over previous
//
#include <hip/hip_runtime.h>
#include <math.h>

#define HW 512
#define NB 16
#define TX 64           // tile width
#define TY 64           // tile height
#define LDSW 72         // TX + 8 (4-col halo left, 4 right; float4-aligned)
#define LDSH 70         // TY + 6
#define N_PIX (NB * HW * HW)   // 4194304
#define NBLK (8 * 8 * NB)      // 1024 phase-1 blocks

using f32x4 = __attribute__((ext_vector_type(4))) float;

// Force a float into an SGPR (uniform across wave).
__device__ __forceinline__ float sgpr_f(float v) {
    return __uint_as_float(__builtin_amdgcn_readfirstlane(__float_as_uint(v)));
}

// Phase 1: 64x64 tile per block; thread = 4 cols x 4 rows (4x4 output patch).
// dif via identity: sum w*relu(v-c) = sum w*max(v,c) - c*sum(w)  (2 ops/tap).
// Window rows stream through registers as 3 aligned ds_read_b128 per row.
// launch_bounds (256,2): VGPR cap 256 so the ~90-float live set stays in
// registers (the (256,4) build squeezed to 64 VGPRs -> spill/remat traffic).
// Plain (cached) float4 stores: nt 16B stores caused sub-line RMW traffic
// (WRITE 113.5 MiB vs 48 ideal, FETCH 48 vs 18 in round-2 counters).
__global__ __launch_bounds__(256, 2) void li_phase1(
    const float* __restrict__ x, const float* __restrict__ kw,
    float* __restrict__ out_ratio, float* __restrict__ out_avg,
    float* __restrict__ out_dif, float* __restrict__ partials)
{
    __shared__ float tile[LDSH * LDSW];   // 20160 B
    __shared__ float wsum[4];

    const int tid = threadIdx.x;
    const int bx = blockIdx.x, by = blockIdx.y, b = blockIdx.z;
    const int x0 = bx * TX, y0 = by * TY;
    const float* xb = x + (size_t)b * (HW * HW);

    // 49 weights pinned to SGPRs; W = sum of all weights (center weight is 0).
    float w[49];
    float W = 0.f;
#pragma unroll
    for (int i = 0; i < 49; i++) { w[i] = sgpr_f(kw[i]); W += w[i]; }

    // Stage 70 x 72 tile with zero halo, float4 granularity.
    for (int idx = tid; idx < LDSH * (LDSW / 4); idx += 256) {
        int r = idx / (LDSW / 4);
        int c4 = idx - r * (LDSW / 4);
        int gy = y0 - 3 + r;
        int gx = x0 - 4 + c4 * 4;
        float4 v = make_float4(0.f, 0.f, 0.f, 0.f);
        if ((unsigned)gy < HW && (unsigned)gx < HW)
            v = *(const float4*)(xb + gy * HW + gx);
        *(float4*)&tile[r * LDSW + c4 * 4] = v;
    }
    __syncthreads();

    const int cx = tid & 15;         // column group: output cols 4cx..4cx+3
    const int cy = tid >> 4;         // row group:    output rows 4cy..4cy+3
    const int colw = 4 * cx;         // LDS word col of v[0] (= tile col - 4)
    const int row0 = 4 * cy;         // first streamed LDS row

    // Centers: 4 aligned float4 loads (LDS cols colw+4..colw+7 = own columns).
    float cen[16];
#pragma unroll
    for (int p = 0; p < 4; p++) {
        float4 c4v = *(const float4*)&tile[(row0 + 3 + p) * LDSW + colw + 4];
        cen[p*4+0] = c4v.x; cen[p*4+1] = c4v.y; cen[p*4+2] = c4v.z; cen[p*4+3] = c4v.w;
    }

    float dif[16], bsum[16];
#pragma unroll
    for (int k = 0; k < 16; k++) { dif[k] = 0.f; bsum[k] = 0.f; }

    // Stream 10 window rows; 3 aligned b128 per row, compiler-scheduled.
    // Row covers LDS words colw..colw+11 (we need colw+1..colw+10).
#pragma unroll
    for (int r = 0; r < 10; r++) {
        const float* base = &tile[(row0 + r) * LDSW + colw];
        float4 q0 = *(const float4*)base;
        float4 q1 = *(const float4*)(base + 4);
        float4 q2 = *(const float4*)(base + 8);
        float v[12] = {q0.x, q0.y, q0.z, q0.w,
                       q1.x, q1.y, q1.z, q1.w,
                       q2.x, q2.y, q2.z, q2.w};

        // Sliding 7-wide row sums for the 4 output columns.
        float s0 = ((v[1] + v[2]) + (v[3] + v[4])) + ((v[5] + v[6]) + v[7]);
        float s1 = s0 + (v[8]  - v[1]);
        float s2 = s1 + (v[9]  - v[2]);
        float s3 = s2 + (v[10] - v[3]);

#pragma unroll
        for (int p = 0; p < 4; p++) {
            const int di = r - p;              // window row index 0..6
            if (di < 0 || di >= 7) continue;   // compile-time resolved
            bsum[p*4+0] += s0; bsum[p*4+1] += s1;
            bsum[p*4+2] += s2; bsum[p*4+3] += s3;
#pragma unroll
            for (int dj = 0; dj < 7; dj++) {
                if (di == 3 && dj == 3) continue;   // center weight == 0
                const float wv = w[di*7+dj];
#pragma unroll
                for (int j = 0; j < 4; j++)
                    dif[p*4+j] = fmaf(wv, fmaxf(v[1+j+dj], cen[p*4+j]), dif[p*4+j]);
            }
        }
    }

    // Epilogue: plain float4 stores (full-line, write-combined in L2).
    const size_t gbase = (size_t)b * (HW * HW) + (size_t)(y0 + row0) * HW + x0 + colw;
    float ss = 0.f;
#pragma unroll
    for (int p = 0; p < 4; p++) {
        float av[4], dv[4], rv[4];
#pragma unroll
        for (int j = 0; j < 4; j++) {
            const int k = p*4+j;
            av[j] = __expf(-bsum[k] * (1.0f / 49.0f));
            dv[j] = fmaf(-W, cen[k], dif[k]);            // subtract c*sum(w)
            const float spv = 0.1f * av[j] + 0.9f * dv[j];  // > 0 always
            rv[j] = cen[k] * __builtin_amdgcn_rcpf(spv);
            ss = fmaf(spv, spv, ss);
        }
        const size_t gi = gbase + (size_t)p * HW;
        *(f32x4*)(out_avg + gi)   = (f32x4){av[0], av[1], av[2], av[3]};
        *(f32x4*)(out_dif + gi)   = (f32x4){dv[0], dv[1], dv[2], dv[3]};
        *(f32x4*)(out_ratio + gi) = (f32x4){rv[0], rv[1], rv[2], rv[3]};
    }

    // Block reduction of ss -> partials[bid].
#pragma unroll
    for (int off = 32; off > 0; off >>= 1)
        ss += __shfl_down(ss, off, 64);
    if ((tid & 63) == 0) wsum[tid >> 6] = ss;
    __syncthreads();
    if (tid == 0)
        partials[bx + 8 * (by + 8 * b)] = (wsum[0] + wsum[1]) + (wsum[2] + wsum[3]);
}

// Phase 2 (reduce fused): each block sums the 1024 partials itself (L2-resident,
// 4 KB), then masks its 4096-element slice in place: mask = (ratio > 1/sqrt(ss)).
__global__ __launch_bounds__(256) void li_phase2(
    const float* __restrict__ partials, float* __restrict__ io)
{
    __shared__ float wsum[4];
    __shared__ float s_inv;
    const int tid = threadIdx.x;

    float s = 0.f;
#pragma unroll
    for (int i = 0; i < NBLK / 256; i++)
        s += partials[tid + i * 256];
#pragma unroll
    for (int off = 32; off > 0; off >>= 1)
        s += __shfl_down(s, off, 64);
    if ((tid & 63) == 0) wsum[tid >> 6] = s;
    __syncthreads();
    if (tid == 0)
        s_inv = 1.0f / sqrtf((wsum[0] + wsum[1]) + (wsum[2] + wsum[3]));
    __syncthreads();

    const float inv = s_inv;
    const int base = blockIdx.x * 4096 + tid * 4;
#pragma unroll
    for (int k = 0; k < 4; k++) {
        const int i = base + k * 1024;
        float4 r = *(const float4*)(io + i);
        float4 m;
        m.x = (r.x > inv) ? 1.f : 0.f;
        m.y = (r.y > inv) ? 1.f : 0.f;
        m.z = (r.z > inv) ? 1.f : 0.f;
        m.w = (r.w > inv) ? 1.f : 0.f;
        *(float4*)(io + i) = m;
    }
}

extern "C" void kernel_launch(void* const* d_in, const int* in_sizes, int n_in,
                              void* d_out, int out_size, void* d_ws, size_t ws_size,
                              hipStream_t stream) {
    const float* x  = (const float*)d_in[0];
    const float* kw = (const float*)d_in[1];
    float* out   = (float*)d_out;
    float* ratio = out;                       // becomes mask after phase 2
    float* avg   = out + N_PIX;
    float* dif   = out + 2 * (size_t)N_PIX;
    float* ws    = (float*)d_ws;              // [0,NBLK): partials (fully written)

    dim3 g(HW / TX, HW / TY, NB);   // 8 x 8 x 16 = 1024 blocks
    li_phase1<<<g, 256, 0, stream>>>(x, kw, ratio, avg, dif, ws);
    li_phase2<<<N_PIX / 4096, 256, 0, stream>>>(ws, ratio);
}